// Round 11
// baseline (273.597 us; speedup 1.0000x reference)
//
#include <hip/hip_runtime.h>
#include <hip/hip_bf16.h>

// SparseFactorisationDense: out = relu(scaling * (x @ (k0*m0) @ (k1*m1) @ (k2*m2)) + bias)
// B=8192, D=U=2048.
// R11 = R10 + register double-buffered fragments: phase p issues the 12
// ds_read_b128 for phase p+1 into the inactive frag set, MFMAs run from the
// active set (register-only) -> LDS service overlaps the MFMA burst
// (phase = max(LDS,MFMA) instead of sum).
//   - uniform gate: vmcnt(4) at EVERY phase end before BAR (pre-barrier gating
//     preserves cross-wave DMA visibility, R9/R10-proven). VM0 at p=61 end.
//   - ledger (sequential, verified): outstanding at each phase end =
//     [half read next phase (4), half after (4)] -> VM4 drains exactly the
//     half-tile whose fragments are read next phase.
//   - phase p stages: p%4==0: t1h1->buf1kh1; 1: t2h0->buf0kh0; 2: t2h1->buf0kh1;
//     3: t3h0->buf1kh0  (t1=2it+1,t2=2it+2,t3=2it+3). Stage/read regions of the
//     same phase disjoint; staged region's last readers 2 phases + LGK0 back.
//   - everything else as R10: 16x16 MFMA operand-swapped, slot-XOR swizzle,
//     T1 XCD swizzle, gload_lds staging, packed epilogue.

typedef __attribute__((ext_vector_type(8))) short  short8;
typedef __attribute__((ext_vector_type(8))) ushort ushort8v;
typedef __attribute__((ext_vector_type(4))) float  f32x4;

#define KD 2048
#define ND 2048

__device__ __forceinline__ ushort f2b(float f) {      // fp32 -> bf16 RNE
    union { float f; unsigned u; } v; v.f = f;
    unsigned r = v.u + 0x7fffu + ((v.u >> 16) & 1u);
    return (ushort)(r >> 16);
}

__device__ __forceinline__ void gload16(const ushort* g, ushort* l) {
    __builtin_amdgcn_global_load_lds(
        (const __attribute__((address_space(1))) void*)g,
        (__attribute__((address_space(3))) void*)l, 16, 0, 0);
}

// ---- x: fp32 -> bf16, 8 elems/thread
__global__ __launch_bounds__(256)
void convx(const float* __restrict__ x, ushort* __restrict__ xb)
{
    const size_t i = (size_t)blockIdx.x * 256 + threadIdx.x;
    const float4* src = reinterpret_cast<const float4*>(x) + i * 2;
    const float4 f0 = src[0], f1 = src[1];
    ushort8v u;
    u[0]=f2b(f0.x); u[1]=f2b(f0.y); u[2]=f2b(f0.z); u[3]=f2b(f0.w);
    u[4]=f2b(f1.x); u[5]=f2b(f1.y); u[6]=f2b(f1.z); u[7]=f2b(f1.w);
    reinterpret_cast<ushort8v*>(xb)[i] = u;
}

// ---- masked-weight transpose+convert for all 3 layers (blockIdx.z picks layer)
__global__ __launch_bounds__(256)
void convT3(const float* __restrict__ k0w, const float* __restrict__ k1w,
            const float* __restrict__ k2w, const float* __restrict__ m0w,
            const float* __restrict__ m1w, const float* __restrict__ m2w,
            ushort* __restrict__ wbT)
{
    const int z = blockIdx.z;
    const float* kw = z == 0 ? k0w : (z == 1 ? k1w : k2w);
    const float* mw = z == 0 ? m0w : (z == 1 ? m1w : m2w);
    ushort* o = wbT + (size_t)z * KD * ND;

    __shared__ ushort t[32][36];
    const int tid = threadIdx.x;
    const int bk = blockIdx.x * 32, bn = blockIdx.y * 32;
    {
        const int r = tid >> 3, c = (tid & 7) * 4;
        const size_t g = (size_t)(bk + r) * ND + bn + c;
        const float4 kv = *reinterpret_cast<const float4*>(kw + g);
        const float4 mv = *reinterpret_cast<const float4*>(mw + g);
        t[r][c + 0] = f2b(kv.x * mv.x);
        t[r][c + 1] = f2b(kv.y * mv.y);
        t[r][c + 2] = f2b(kv.z * mv.z);
        t[r][c + 3] = f2b(kv.w * mv.w);
    }
    __syncthreads();
    {
        const int n = tid >> 3, kq = (tid & 7) * 4;
        ushort4 ov;
        ov.x = t[kq + 0][n]; ov.y = t[kq + 1][n];
        ov.z = t[kq + 2][n]; ov.w = t[kq + 3][n];
        *reinterpret_cast<ushort4*>(&o[(size_t)(bn + n) * KD + bk + kq]) = ov;
    }
}

// ================= 256x256 reg-dbuf pipelined GEMM (16x16 MFMA) =================
// C[M][N] = A[M][K] @ BT[N][K]^T, all bf16 in, fp32 accum.
template<int EPI>
__global__ __launch_bounds__(512, 2)
void gemm256(const ushort* __restrict__ A, const ushort* __restrict__ BT,
             void* __restrict__ Cout,
             const float* __restrict__ scaling, const float* __restrict__ bias)
{
    // [buf][op 0=A 1=B][kh][row*32 + k]  = 128 KiB
    __shared__ ushort S[2][2][2][256 * 32];

    const int tid  = threadIdx.x;
    const int lane = tid & 63;
    const int wid  = tid >> 6;                 // 0..7
    const int wr   = wid >> 2, wc = wid & 3;   // 2x4 wave grid: 128x64 per wave
    const int l15  = lane & 15;
    const int kq   = lane >> 4;                // fragment k-slot 0..3
    // T1: bijective XCD swizzle (256 blocks % 8 XCDs == 0)
    const int id   = blockIdx.x;
    const int swz  = (id & 7) * 32 + (id >> 3);
    const int bn   = (swz & 7) * 256;          // 8 N-blocks
    const int bm   = (swz >> 3) * 256;         // 32 M-blocks
    const int srow = lane >> 2;                // staging: 16 rows / gload
    const int wrow = wid * 32;                 // this wave's 32-row staging slice
    // both-sides involution: physical 16B slot = logical slot ^ ((row>>1)&3)
    const int ssw  = ((lane & 3) ^ ((srow >> 1) & 3)) * 8;  // staged source k-off
    const int rsw  = (kq ^ ((l15 >> 1) & 3)) * 8;           // fragment read k-off

    f32x4 acc[8][4] = {};
    // two fragment register sets (a/b): x* = A-frags, y* = B-frags
    short8 xa0, xa1, xa2, xa3, xa4, xa5, xa6, xa7, ya0, ya1, ya2, ya3;
    short8 xb0, xb1, xb2, xb3, xb4, xb5, xb6, xb7, yb0, yb1, yb2, yb3;

#define STAGE(op, bufl, kh, tile, G, g0) do {                                        \
    gload16(G + (size_t)((g0) + wrow + srow)      * KD + (tile)*64 + (kh)*32 + ssw,  \
            &S[bufl][op][kh][(wrow)      * 32]);                                     \
    gload16(G + (size_t)((g0) + wrow + 16 + srow) * KD + (tile)*64 + (kh)*32 + ssw,  \
            &S[bufl][op][kh][(wrow + 16) * 32]);                                     \
  } while (0)

#define BAR()  asm volatile("s_barrier" ::: "memory")
#define VM4()  asm volatile("s_waitcnt vmcnt(4)" ::: "memory")
#define VM0()  asm volatile("s_waitcnt vmcnt(0)" ::: "memory")
#define LGK0() asm volatile("s_waitcnt lgkmcnt(0)" ::: "memory")
#define SB()   __builtin_amdgcn_sched_barrier(0)
#define PRI1() __builtin_amdgcn_s_setprio(1)
#define PRI0() __builtin_amdgcn_s_setprio(0)

#define FA(bufl, kh, m) (*(const short8*)&S[bufl][0][kh][(wr*128 + (m)*16 + l15)*32 + rsw])
#define FB(bufl, kh, n) (*(const short8*)&S[bufl][1][kh][(wc*64  + (n)*16 + l15)*32 + rsw])

#define MF(a_, b_, c_) __builtin_amdgcn_mfma_f32_16x16x32_bf16(a_, b_, c_, 0, 0, 0)

#define READS(X, Y, bufl, kh)                                                         \
    Y##0 = FB(bufl,kh,0); Y##1 = FB(bufl,kh,1);                                       \
    Y##2 = FB(bufl,kh,2); Y##3 = FB(bufl,kh,3);                                       \
    X##0 = FA(bufl,kh,0); X##1 = FA(bufl,kh,1);                                       \
    X##2 = FA(bufl,kh,2); X##3 = FA(bufl,kh,3);                                       \
    X##4 = FA(bufl,kh,4); X##5 = FA(bufl,kh,5);                                       \
    X##6 = FA(bufl,kh,6); X##7 = FA(bufl,kh,7);

// operand-swapped: acc[m][n] += B^T-frag x A-frag -> D row=n-col-quad, col=m
#define MMROW(m, xm, Y)                                                               \
    acc[m][0] = MF(Y##0, xm, acc[m][0]);                                              \
    acc[m][1] = MF(Y##1, xm, acc[m][1]);                                              \
    acc[m][2] = MF(Y##2, xm, acc[m][2]);                                              \
    acc[m][3] = MF(Y##3, xm, acc[m][3]);

#define MMALL(X, Y)                                                                   \
    MMROW(0, X##0, Y) MMROW(1, X##1, Y) MMROW(2, X##2, Y) MMROW(3, X##3, Y)           \
    MMROW(4, X##4, Y) MMROW(5, X##5, Y) MMROW(6, X##6, Y) MMROW(7, X##7, Y)

// Phase: reads for NEXT phase into (LX,LY) + stage + MFMAs from (CX,CY) + gate.
#define PH(LX, LY, lbuf, lkh, STG, CX, CY, GATE) do {                                 \
    READS(LX, LY, lbuf, lkh);                                                         \
    STG; SB();                                                                        \
    PRI1(); MMALL(CX, CY); PRI0(); SB();                                              \
    LGK0(); GATE; BAR();                                                              \
  } while (0)

    // ---- prologue: stage t0h0, t0h1, t1h0 (12 loads); gate t0 (both halves)
    STAGE(0, 0, 0, 0, A,  bm); STAGE(1, 0, 0, 0, BT, bn);
    STAGE(0, 0, 1, 0, A,  bm); STAGE(1, 0, 1, 0, BT, bn);
    STAGE(1, 1, 0, 1, BT, bn); STAGE(0, 1, 0, 1, A,  bm);
    VM4();   // drains t0h0 + t0h1; t1h0 (4) stays in flight
    BAR();
    READS(xa, ya, 0, 0);                       // t0h0 fragments -> set a

    for (int it = 0; it < 15; ++it) {          // phases p = 0..59
        const int t1 = 2 * it + 1, t2 = 2 * it + 2, t3 = 2 * it + 3;
        PH(xb, yb, 0, 1, STAGE(1,1,1,t1,BT,bn); STAGE(0,1,1,t1,A,bm), xa, ya, VM4());
        PH(xa, ya, 1, 0, STAGE(1,0,0,t2,BT,bn); STAGE(0,0,0,t2,A,bm), xb, yb, VM4());
        PH(xb, yb, 1, 1, STAGE(1,0,1,t2,BT,bn); STAGE(0,0,1,t2,A,bm), xa, ya, VM4());
        PH(xa, ya, 0, 0, STAGE(1,1,0,t3,BT,bn); STAGE(0,1,0,t3,A,bm), xb, yb, VM4());
    }
    // ---- tail: p=60..63 (tiles 30/31 in buf0/buf1)
    PH(xb, yb, 0, 1, STAGE(1,1,1,31,BT,bn); STAGE(0,1,1,31,A,bm), xa, ya, VM4());
    PH(xa, ya, 1, 0, , xb, yb, VM0());
    PH(xb, yb, 1, 1, , xa, ya, );
    PRI1(); MMALL(xb, yb); PRI0();             // p=63: MFMA only

    // ---- epilogue (swapped layout): lane covers row m = l15, cols kq*4..+3
    const float sc = EPI ? scaling[0] : 0.f;
#pragma unroll
    for (int m = 0; m < 8; ++m) {
        const size_t grow = (size_t)(bm + wr * 128 + m * 16 + l15);
#pragma unroll
        for (int n = 0; n < 4; ++n) {
            const int gcol = bn + wc * 64 + n * 16 + kq * 4;
            if constexpr (EPI) {
                const float4 bv = *reinterpret_cast<const float4*>(bias + gcol);
                float4 v;
                v.x = fmaxf(fmaf(sc, acc[m][n][0], bv.x), 0.f);
                v.y = fmaxf(fmaf(sc, acc[m][n][1], bv.y), 0.f);
                v.z = fmaxf(fmaf(sc, acc[m][n][2], bv.z), 0.f);
                v.w = fmaxf(fmaf(sc, acc[m][n][3], bv.w), 0.f);
                *reinterpret_cast<float4*>((float*)Cout + grow * ND + gcol) = v;
            } else {
                ushort4 v;
                v.x = f2b(acc[m][n][0]); v.y = f2b(acc[m][n][1]);
                v.z = f2b(acc[m][n][2]); v.w = f2b(acc[m][n][3]);
                *reinterpret_cast<ushort4*>((ushort*)Cout + grow * ND + gcol) = v;
            }
        }
    }
#undef STAGE
#undef PH
#undef MF
#undef MMROW
#undef MMALL
#undef READS
#undef FA
#undef FB
}

extern "C" void kernel_launch(void* const* d_in, const int* in_sizes, int n_in,
                              void* d_out, int out_size, void* d_ws, size_t ws_size,
                              hipStream_t stream)
{
    // inputs: x, k0, k1, k2, m0, m1, m2, scaling, bias
    const float* x    = (const float*)d_in[0];
    const float* k0w  = (const float*)d_in[1];
    const float* k1w  = (const float*)d_in[2];
    const float* k2w  = (const float*)d_in[3];
    const float* m0w  = (const float*)d_in[4];
    const float* m1w  = (const float*)d_in[5];
    const float* m2w  = (const float*)d_in[6];
    const float* sc   = (const float*)d_in[7];
    const float* bias = (const float*)d_in[8];

    const int Md = in_sizes[0] / KD;               // 8192
    const size_t NE = (size_t)Md * KD;             // 16.7M elems

    // d_out (64MB fp32): [act1 bf16 32MB][x_bf16 32MB]; GEMM3 overwrites all.
    ushort* act1 = (ushort*)d_out;
    ushort* xb   = (ushort*)d_out + NE;
    float*  out  = (float*)d_out;
    // ws: [act2 bf16 32MB][wbT0 8MB][wbT1 8MB][wbT2 8MB] = 56MB
    ushort* act2 = (ushort*)d_ws;
    ushort* wbT  = (ushort*)d_ws + NE;

    dim3 bl(256);
    dim3 gX(NE / (256 * 8));                       // 8192
    dim3 gT(KD / 32, ND / 32, 3);                  // (64,64,3)
    dim3 gG((ND / 256) * (Md / 256)), bG(512);     // 256 blocks 1D (XCD swizzle inside)

    convx <<<gX, bl, 0, stream>>>(x, xb);
    convT3<<<gT, bl, 0, stream>>>(k0w, k1w, k2w, m0w, m1w, m2w, wbT);

    gemm256<0><<<gG, bG, 0, stream>>>(xb,   wbT,                     act1, nullptr, nullptr);
    gemm256<0><<<gG, bG, 0, stream>>>(act1, wbT + (size_t)KD * ND,     act2, nullptr, nullptr);
    gemm256<1><<<gG, bG, 0, stream>>>(act2, wbT + (size_t)2 * KD * ND, out,  sc, bias);
}

// Round 13
// 218.943 us; speedup vs baseline: 1.2496x; 1.2496x over previous
//
#include <hip/hip_runtime.h>
#include <hip/hip_bf16.h>

// SparseFactorisationDense: out = relu(scaling * (x @ (k0*m0) @ (k1*m1) @ (k2*m2)) + bias)
// B=8192, D=U=2048.
// R13 = R12 resubmit (container died while pushing, before any kernel ran;
// ledger re-audited: no hang source).
// R12 = R10 with mid-tile barriers removed (one s_barrier per K-tile).
//   Theory: R10's per-phase BAR lockstepped all 8 waves -> LDS read bursts and
//   MFMA bursts serialized CU-wide (phase = LDS + MFMA). With one barrier per
//   K-tile and the whole next tile staged into the OTHER LDS buffer, there are
//   no intra-interval hazards (reads: buf b only; DMA: buf b^1 only) -> waves
//   drift within the interval and LDS service overlaps MFMA.
//   - interval: {reads kh0, stage(t+1,h0), MFMA kh0, reads kh1, stage(t+1,h1),
//     MFMA kh1, LGK0, VM0, BAR}
//   - VM0 gate is ~free: gloads issued >=1 sub-phase earlier, L2-resident
//   - registers = R10 (single frag set, no spill; R11's dual-set spilled)
//   - 16x16 MFMA operand-swapped, slot-XOR LDS swizzle (0 conflicts), T1 XCD
//     swizzle, gload_lds staging, packed epilogue: all unchanged from R10

typedef __attribute__((ext_vector_type(8))) short  short8;
typedef __attribute__((ext_vector_type(8))) ushort ushort8v;
typedef __attribute__((ext_vector_type(4))) float  f32x4;

#define KD 2048
#define ND 2048

__device__ __forceinline__ ushort f2b(float f) {      // fp32 -> bf16 RNE
    union { float f; unsigned u; } v; v.f = f;
    unsigned r = v.u + 0x7fffu + ((v.u >> 16) & 1u);
    return (ushort)(r >> 16);
}

__device__ __forceinline__ void gload16(const ushort* g, ushort* l) {
    __builtin_amdgcn_global_load_lds(
        (const __attribute__((address_space(1))) void*)g,
        (__attribute__((address_space(3))) void*)l, 16, 0, 0);
}

// ---- x: fp32 -> bf16, 8 elems/thread
__global__ __launch_bounds__(256)
void convx(const float* __restrict__ x, ushort* __restrict__ xb)
{
    const size_t i = (size_t)blockIdx.x * 256 + threadIdx.x;
    const float4* src = reinterpret_cast<const float4*>(x) + i * 2;
    const float4 f0 = src[0], f1 = src[1];
    ushort8v u;
    u[0]=f2b(f0.x); u[1]=f2b(f0.y); u[2]=f2b(f0.z); u[3]=f2b(f0.w);
    u[4]=f2b(f1.x); u[5]=f2b(f1.y); u[6]=f2b(f1.z); u[7]=f2b(f1.w);
    reinterpret_cast<ushort8v*>(xb)[i] = u;
}

// ---- masked-weight transpose+convert for all 3 layers (blockIdx.z picks layer)
__global__ __launch_bounds__(256)
void convT3(const float* __restrict__ k0w, const float* __restrict__ k1w,
            const float* __restrict__ k2w, const float* __restrict__ m0w,
            const float* __restrict__ m1w, const float* __restrict__ m2w,
            ushort* __restrict__ wbT)
{
    const int z = blockIdx.z;
    const float* kw = z == 0 ? k0w : (z == 1 ? k1w : k2w);
    const float* mw = z == 0 ? m0w : (z == 1 ? m1w : m2w);
    ushort* o = wbT + (size_t)z * KD * ND;

    __shared__ ushort t[32][36];
    const int tid = threadIdx.x;
    const int bk = blockIdx.x * 32, bn = blockIdx.y * 32;
    {
        const int r = tid >> 3, c = (tid & 7) * 4;
        const size_t g = (size_t)(bk + r) * ND + bn + c;
        const float4 kv = *reinterpret_cast<const float4*>(kw + g);
        const float4 mv = *reinterpret_cast<const float4*>(mw + g);
        t[r][c + 0] = f2b(kv.x * mv.x);
        t[r][c + 1] = f2b(kv.y * mv.y);
        t[r][c + 2] = f2b(kv.z * mv.z);
        t[r][c + 3] = f2b(kv.w * mv.w);
    }
    __syncthreads();
    {
        const int n = tid >> 3, kq = (tid & 7) * 4;
        ushort4 ov;
        ov.x = t[kq + 0][n]; ov.y = t[kq + 1][n];
        ov.z = t[kq + 2][n]; ov.w = t[kq + 3][n];
        *reinterpret_cast<ushort4*>(&o[(size_t)(bn + n) * KD + bk + kq]) = ov;
    }
}

// ================= 256x256 one-barrier-per-tile GEMM (16x16 MFMA) =================
// C[M][N] = A[M][K] @ BT[N][K]^T, all bf16 in, fp32 accum.
template<int EPI>
__global__ __launch_bounds__(512, 2)
void gemm256(const ushort* __restrict__ A, const ushort* __restrict__ BT,
             void* __restrict__ Cout,
             const float* __restrict__ scaling, const float* __restrict__ bias)
{
    // [buf][op 0=A 1=B][kh][row*32 + k]  = 128 KiB
    __shared__ ushort S[2][2][2][256 * 32];

    const int tid  = threadIdx.x;
    const int lane = tid & 63;
    const int wid  = tid >> 6;                 // 0..7
    const int wr   = wid >> 2, wc = wid & 3;   // 2x4 wave grid: 128x64 per wave
    const int l15  = lane & 15;
    const int kq   = lane >> 4;                // fragment k-slot 0..3
    // T1: bijective XCD swizzle (256 blocks % 8 XCDs == 0)
    const int id   = blockIdx.x;
    const int swz  = (id & 7) * 32 + (id >> 3);
    const int bn   = (swz & 7) * 256;          // 8 N-blocks
    const int bm   = (swz >> 3) * 256;         // 32 M-blocks
    const int srow = lane >> 2;                // staging: 16 rows / gload
    const int wrow = wid * 32;                 // this wave's 32-row staging slice
    // both-sides involution: physical 16B slot = logical slot ^ ((row>>1)&3)
    const int ssw  = ((lane & 3) ^ ((srow >> 1) & 3)) * 8;  // staged source k-off
    const int rsw  = (kq ^ ((l15 >> 1) & 3)) * 8;           // fragment read k-off

    f32x4 acc[8][4] = {};
    short8 xa0, xa1, xa2, xa3, xa4, xa5, xa6, xa7, ya0, ya1, ya2, ya3;

#define STAGE(op, bufl, kh, tile, G, g0) do {                                        \
    gload16(G + (size_t)((g0) + wrow + srow)      * KD + (tile)*64 + (kh)*32 + ssw,  \
            &S[bufl][op][kh][(wrow)      * 32]);                                     \
    gload16(G + (size_t)((g0) + wrow + 16 + srow) * KD + (tile)*64 + (kh)*32 + ssw,  \
            &S[bufl][op][kh][(wrow + 16) * 32]);                                     \
  } while (0)

#define BAR()  asm volatile("s_barrier" ::: "memory")
#define VM0()  asm volatile("s_waitcnt vmcnt(0)" ::: "memory")
#define LGK0() asm volatile("s_waitcnt lgkmcnt(0)" ::: "memory")
#define SB()   __builtin_amdgcn_sched_barrier(0)
#define PRI1() __builtin_amdgcn_s_setprio(1)
#define PRI0() __builtin_amdgcn_s_setprio(0)

#define FA(bufl, kh, m) (*(const short8*)&S[bufl][0][kh][(wr*128 + (m)*16 + l15)*32 + rsw])
#define FB(bufl, kh, n) (*(const short8*)&S[bufl][1][kh][(wc*64  + (n)*16 + l15)*32 + rsw])

#define MF(a_, b_, c_) __builtin_amdgcn_mfma_f32_16x16x32_bf16(a_, b_, c_, 0, 0, 0)

// ladder order: B-frags first, then A-frags (first MFMA needs reads #1-5)
#define READS(bufl, kh)                                                               \
    ya0 = FB(bufl,kh,0); ya1 = FB(bufl,kh,1);                                         \
    ya2 = FB(bufl,kh,2); ya3 = FB(bufl,kh,3);                                         \
    xa0 = FA(bufl,kh,0); xa1 = FA(bufl,kh,1);                                         \
    xa2 = FA(bufl,kh,2); xa3 = FA(bufl,kh,3);                                         \
    xa4 = FA(bufl,kh,4); xa5 = FA(bufl,kh,5);                                         \
    xa6 = FA(bufl,kh,6); xa7 = FA(bufl,kh,7);

// operand-swapped: acc[m][n] += B^T-frag x A-frag -> D row=n-col-quad, col=m
#define MMROW(m, xm)                                                                  \
    acc[m][0] = MF(ya0, xm, acc[m][0]);                                               \
    acc[m][1] = MF(ya1, xm, acc[m][1]);                                               \
    acc[m][2] = MF(ya2, xm, acc[m][2]);                                               \
    acc[m][3] = MF(ya3, xm, acc[m][3]);

#define MMALL()                                                                       \
    MMROW(0, xa0) MMROW(1, xa1) MMROW(2, xa2) MMROW(3, xa3)                           \
    MMROW(4, xa4) MMROW(5, xa5) MMROW(6, xa6) MMROW(7, xa7)

// One K-tile interval: 2 sub-phases (kh0, kh1), stage full next tile, 1 barrier.
#define INTERVAL(bufl, STG1, STG2, GATE) do {                                         \
    STG1;                                                                             \
    READS(bufl, 0);                                                                   \
    PRI1(); MMALL(); PRI0();                                                          \
    STG2;                                                                             \
    READS(bufl, 1);                                                                   \
    PRI1(); MMALL(); PRI0(); SB();                                                    \
    LGK0(); GATE; BAR();                                                              \
  } while (0)

    // ---- prologue: stage tile 0 into buf0, drain, barrier
    STAGE(0, 0, 0, 0, A,  bm); STAGE(1, 0, 0, 0, BT, bn);
    STAGE(0, 0, 1, 0, A,  bm); STAGE(1, 0, 1, 0, BT, bn);
    VM0();
    BAR();

    // ---- main: tiles 0..30 compute, each staging tile t+1 into buf^1
    for (int t = 0; t < 31; ++t) {
        const int bf = t & 1;
        INTERVAL(bf,
                 STAGE(0, bf ^ 1, 0, t + 1, A, bm); STAGE(1, bf ^ 1, 0, t + 1, BT, bn),
                 STAGE(0, bf ^ 1, 1, t + 1, A, bm); STAGE(1, bf ^ 1, 1, t + 1, BT, bn),
                 VM0());
    }
    // ---- tail: tile 31 (buf1), no staging, no barrier
    READS(1, 0);
    PRI1(); MMALL(); PRI0();
    READS(1, 1);
    PRI1(); MMALL(); PRI0();

    // ---- epilogue (swapped layout): lane covers row m = l15, cols kq*4..+3
    const float sc = EPI ? scaling[0] : 0.f;
#pragma unroll
    for (int m = 0; m < 8; ++m) {
        const size_t grow = (size_t)(bm + wr * 128 + m * 16 + l15);
#pragma unroll
        for (int n = 0; n < 4; ++n) {
            const int gcol = bn + wc * 64 + n * 16 + kq * 4;
            if constexpr (EPI) {
                const float4 bv = *reinterpret_cast<const float4*>(bias + gcol);
                float4 v;
                v.x = fmaxf(fmaf(sc, acc[m][n][0], bv.x), 0.f);
                v.y = fmaxf(fmaf(sc, acc[m][n][1], bv.y), 0.f);
                v.z = fmaxf(fmaf(sc, acc[m][n][2], bv.z), 0.f);
                v.w = fmaxf(fmaf(sc, acc[m][n][3], bv.w), 0.f);
                *reinterpret_cast<float4*>((float*)Cout + grow * ND + gcol) = v;
            } else {
                ushort4 v;
                v.x = f2b(acc[m][n][0]); v.y = f2b(acc[m][n][1]);
                v.z = f2b(acc[m][n][2]); v.w = f2b(acc[m][n][3]);
                *reinterpret_cast<ushort4*>((ushort*)Cout + grow * ND + gcol) = v;
            }
        }
    }
#undef STAGE
#undef INTERVAL
#undef MF
#undef MMROW
#undef MMALL
#undef READS
#undef FA
#undef FB
}

extern "C" void kernel_launch(void* const* d_in, const int* in_sizes, int n_in,
                              void* d_out, int out_size, void* d_ws, size_t ws_size,
                              hipStream_t stream)
{
    // inputs: x, k0, k1, k2, m0, m1, m2, scaling, bias
    const float* x    = (const float*)d_in[0];
    const float* k0w  = (const float*)d_in[1];
    const float* k1w  = (const float*)d_in[2];
    const float* k2w  = (const float*)d_in[3];
    const float* m0w  = (const float*)d_in[4];
    const float* m1w  = (const float*)d_in[5];
    const float* m2w  = (const float*)d_in[6];
    const float* sc   = (const float*)d_in[7];
    const float* bias = (const float*)d_in[8];

    const int Md = in_sizes[0] / KD;               // 8192
    const size_t NE = (size_t)Md * KD;             // 16.7M elems

    // d_out (64MB fp32): [act1 bf16 32MB][x_bf16 32MB]; GEMM3 overwrites all.
    ushort* act1 = (ushort*)d_out;
    ushort* xb   = (ushort*)d_out + NE;
    float*  out  = (float*)d_out;
    // ws: [act2 bf16 32MB][wbT0 8MB][wbT1 8MB][wbT2 8MB] = 56MB
    ushort* act2 = (ushort*)d_ws;
    ushort* wbT  = (ushort*)d_ws + NE;

    dim3 bl(256);
    dim3 gX(NE / (256 * 8));                       // 8192
    dim3 gT(KD / 32, ND / 32, 3);                  // (64,64,3)
    dim3 gG((ND / 256) * (Md / 256)), bG(512);     // 256 blocks 1D (XCD swizzle inside)

    convx <<<gX, bl, 0, stream>>>(x, xb);
    convT3<<<gT, bl, 0, stream>>>(k0w, k1w, k2w, m0w, m1w, m2w, wbT);

    gemm256<0><<<gG, bG, 0, stream>>>(xb,   wbT,                     act1, nullptr, nullptr);
    gemm256<0><<<gG, bG, 0, stream>>>(act1, wbT + (size_t)KD * ND,     act2, nullptr, nullptr);
    gemm256<1><<<gG, bG, 0, stream>>>(act2, wbT + (size_t)2 * KD * ND, out,  sc, bias);
}